// Round 4
// baseline (273.933 us; speedup 1.0000x reference)
//
#include <hip/hip_runtime.h>

// QuantumRNNCell v6: un-fused; copy-shaped streaming epilogue.
//
//   Evidence: every batched/fused variant (v3-epi, v4.1, v5) caps at 2.4 TB/s
//   while grid-stride streamers (fillBuffer 6.5, m13 copy 6.3) saturate.
//   So: sim and epilogue split; the epilogue is a pure grid-stride loop:
//     - per-thread column (= tid) fixed => fc_w (6 float4) + bias hoisted to
//       registers before the loop, loaded once;
//     - per trip, the q6 row is BLOCK-uniform (row = bid + k*gridDim) =>
//       compiler emits s_load for it (zero vector-load cost);
//     - body = 1 float4 load + 28 FMA + 1 nontemporal float4 store. 16 trips.
//   Sim kernel: one wave per row, lane l = basis state l (verified v4.1/v5
//   gate math), writes q6 (B,6) to d_ws.
//
// Fixed shape: B = 32768, H = 1024 (256 float4 per row).

#define NQ 6

typedef float floatx4 __attribute__((ext_vector_type(4)));

__device__ __forceinline__ float rl(float v, int lane) {
    return __int_as_float(__builtin_amdgcn_readlane(__float_as_int(v), lane));
}

// ---------------- kernel 1: wave-per-row quantum sim ----------------
__global__ __launch_bounds__(256, 4) void qrnn_sim_kernel(
    const float* __restrict__ x,     // (B, 6)
    const float* __restrict__ qw,    // (3, 6)
    float* __restrict__ q6)          // (B, 6) out
{
    const int tid = threadIdx.x;
    const int l   = tid & 63;        // lane = basis state
    const int wv  = tid >> 6;        // wave 0..3
    const int b   = blockIdx.x * 4 + wv;   // this wave's batch row

    // one sincos per wave: lanes 0-5 = x angles, lanes 6-23 = qw angles
    float ang = 0.f;
    if (l < 6)        ang = x[(size_t)b * NQ + l];
    else if (l < 24)  ang = qw[l - 6];
    float sa, ca;
    __sincosf(ang * 0.5f, &sa, &ca);

    float cx[6], sx[6];
    #pragma unroll
    for (int i = 0; i < 6; ++i) { cx[i] = rl(ca, i); sx[i] = rl(sa, i); }

    float re = (l == 0) ? 1.f : 0.f;
    float im = 0.f;

    // encoding: RX(x[i]), RY(x[i+1]), RZ(x[i+2]) on wire i (bit 5-i)
    #pragma unroll
    for (int w = 0; w < 6; ++w) {
        const int m = 1 << (5 - w);
        const float sgn = (l & m) ? 1.f : -1.f;
        float pr = __shfl_xor(re, m), pi = __shfl_xor(im, m);
        float c = cx[w], s = sx[w];
        float nr = c * re + s * pi;
        float ni = c * im - s * pr;
        re = nr; im = ni;
        pr = __shfl_xor(re, m); pi = __shfl_xor(im, m);
        c = cx[(w + 1) % 6]; s = sx[(w + 1) % 6] * sgn;
        nr = c * re + s * pr;
        ni = c * im + s * pi;
        re = nr; im = ni;
        c = cx[(w + 2) % 6];
        const float sg = (l & m) ? -sx[(w + 2) % 6] : sx[(w + 2) % 6];
        nr = c * re + sg * im;
        ni = c * im - sg * re;
        re = nr; im = ni;
    }

    // CNOT-ring composed permutation: new[l] = old[src]
    int src = l;
    #pragma unroll
    for (int q = 5; q >= 0; --q) {
        const int cb = 5 - q, tb = 5 - ((q + 1) % 6);
        src ^= ((src >> cb) & 1) << tb;
    }

    // variational layers: 6x RY(qw[lay][q]) then CNOT ring
    #pragma unroll
    for (int lay = 0; lay < 3; ++lay) {
        #pragma unroll
        for (int q = 0; q < 6; ++q) {
            const int m = 1 << (5 - q);
            const float c = rl(ca, 6 + lay * 6 + q);
            const float s = rl(sa, 6 + lay * 6 + q);
            const float sg = (l & m) ? s : -s;
            const float pr = __shfl_xor(re, m), pi = __shfl_xor(im, m);
            const float nr = c * re + sg * pr;
            const float ni = c * im + sg * pi;
            re = nr; im = ni;
        }
        re = __shfl(re, src);
        im = __shfl(im, src);
    }

    // probabilities -> 6-stage Walsh-Hadamard; q[j] lands at lane 32>>j
    float p = re * re + im * im;
    #pragma unroll
    for (int k = 0; k < 6; ++k) {
        const int m = 1 << k;
        const float t = __shfl_xor(p, m);
        p = (l & m) ? (t - p) : (t + p);
    }
    const int srcl = (l < 6) ? (32 >> l) : 0;
    const float v = __shfl(p, srcl);
    if (l < 6) q6[(size_t)b * NQ + l] = v;
}

// ---------------- kernel 2: grid-stride streaming epilogue ----------------
//   out[row][4t..4t+3] = hx[row][...] + q6[row]·fc_w[...] + fc_b[...]
__global__ __launch_bounds__(256) void qrnn_epi_kernel(
    const float* __restrict__ hx,    // (B, H)
    const float* __restrict__ q6,    // (B, 6)
    const float* __restrict__ fc_w,  // (H, 6)
    const float* __restrict__ fc_b,  // (H,)
    float* __restrict__ out,         // (B, H)
    int B)
{
    const int tid = threadIdx.x;     // float4 column, fixed per thread
    const int nb  = gridDim.x;

    // hoist this column's weights + bias into registers (loop-invariant)
    const float4* w4 = (const float4*)fc_w;
    const int wb = tid * 6;
    const float4 a0 = w4[wb + 0], a1 = w4[wb + 1], a2 = w4[wb + 2];
    const float4 a3 = w4[wb + 3], a4 = w4[wb + 4], a5 = w4[wb + 5];
    const float4 bv = ((const float4*)fc_b)[tid];

    const float4* hx4 = (const float4*)hx;
    floatx4* out4 = (floatx4*)out;

    for (int row = blockIdx.x; row < B; row += nb) {
        // q row is block-uniform -> scalar loads
        const float* qr = q6 + (size_t)row * NQ;
        const float q0 = qr[0], q1 = qr[1], q2 = qr[2];
        const float q3 = qr[3], q4 = qr[4], q5 = qr[5];

        const float4 hv = hx4[(size_t)row * 256 + tid];
        floatx4 res;
        res.x = hv.x + bv.x + q0*a0.x + q1*a0.y + q2*a0.z + q3*a0.w + q4*a1.x + q5*a1.y;
        res.y = hv.y + bv.y + q0*a1.z + q1*a1.w + q2*a2.x + q3*a2.y + q4*a2.z + q5*a2.w;
        res.z = hv.z + bv.z + q0*a3.x + q1*a3.y + q2*a3.z + q3*a3.w + q4*a4.x + q5*a4.y;
        res.w = hv.w + bv.w + q0*a4.z + q1*a4.w + q2*a5.x + q3*a5.y + q4*a5.z + q5*a5.w;
        __builtin_nontemporal_store(res, &out4[(size_t)row * 256 + tid]);
    }
}

extern "C" void kernel_launch(void* const* d_in, const int* in_sizes, int n_in,
                              void* d_out, int out_size, void* d_ws, size_t ws_size,
                              hipStream_t stream) {
    const float* x    = (const float*)d_in[0];   // (B, 6)
    const float* hx   = (const float*)d_in[1];   // (B, H)
    const float* qw   = (const float*)d_in[2];   // (3, 6)
    const float* fc_w = (const float*)d_in[3];   // (H, 6)
    const float* fc_b = (const float*)d_in[4];   // (H,)
    float* out = (float*)d_out;

    const int B = in_sizes[0] / NQ;              // 32768
    // H fixed at 1024 (kernels hardcode 256 float4 per row)

    float* q6 = (float*)d_ws;                    // (B, 6) scratch, 768 KB

    qrnn_sim_kernel<<<B / 4, 256, 0, stream>>>(x, qw, q6);
    // 2048 blocks -> 8 blocks/CU, 16 row-trips per thread, copy-shaped stream
    qrnn_epi_kernel<<<2048, 256, 0, stream>>>(hx, q6, fc_w, fc_b, out, B);
}